// Round 2
// baseline (354.640 us; speedup 1.0000x reference)
//
#include <hip/hip_runtime.h>

// Problem constants (fixed by reference setup_inputs):
//   messages: (B=32, E=8192, D=128) f32
//   tgt_indices: (B, E) int32 in [0, N)
//   atom_features_ref: (B, N=2048, D=128) f32  -- shape-only, never read
//   out: (B, N, D) f32 = scatter-add of messages by tgt per batch
#define BB   32
#define EE   8192
#define NN   2048
#define DD   128
#define ACH  64              // atoms per block
#define NCH  (NN / ACH)      // 32 chunks per batch
#define NTHR 512             // 8 waves

__global__ __launch_bounds__(NTHR) void scatter_bin_kernel(
    const float* __restrict__ messages,
    const int*   __restrict__ tgt,
    float*       __restrict__ out)
{
    __shared__ float        acc[ACH * DD];   // 32 KiB accumulation tile
    __shared__ unsigned int lst[EE];         // 32 KiB worst-case edge list
    __shared__ unsigned int cnt;

    const int bid = blockIdx.x;
    const int b   = bid / NCH;
    const int a0  = (bid % NCH) * ACH;
    const int tid = threadIdx.x;

    // ---- Phase 0: zero the accumulator tile (vectorized) ----
    float4* acc4 = (float4*)acc;
    #pragma unroll
    for (int i = tid; i < ACH * DD / 4; i += NTHR)
        acc4[i] = make_float4(0.f, 0.f, 0.f, 0.f);
    if (tid == 0) cnt = 0u;
    __syncthreads();

    // ---- Phase 1: scan this batch's indices, compact matches ----
    const int* idx = tgt + b * EE;
    #pragma unroll
    for (int e = tid; e < EE; e += NTHR) {
        int a = idx[e];
        unsigned int d = (unsigned int)(a - a0);
        if (d < (unsigned int)ACH) {
            unsigned int p = atomicAdd(&cnt, 1u);
            lst[p] = ((unsigned int)e << 6) | d;   // e:13 bits, atom-offset:6 bits
        }
    }
    __syncthreads();

    // ---- Phase 2: gather matched message rows, accumulate in LDS ----
    // 32 consecutive threads own one edge: lane l reads float4 #l of the
    // 512 B row (fully coalesced), then 4 LDS atomic adds.
    const int n    = (int)cnt;
    const int slot = tid >> 5;          // 0..15 edge slots in flight
    const int l    = tid & 31;          // float4 index within row
    const float4* msg4   = (const float4*)messages;
    const size_t  rowbase = (size_t)b * EE;
    for (int i = slot; i < n; i += NTHR / 32) {
        unsigned int ent = lst[i];
        int e = (int)(ent >> 6);
        int a = (int)(ent & 63u);
        float4 v = msg4[(rowbase + (size_t)e) * (DD / 4) + l];
        float* dst = &acc[a * DD + l * 4];
        atomicAdd(dst + 0, v.x);
        atomicAdd(dst + 1, v.y);
        atomicAdd(dst + 2, v.z);
        atomicAdd(dst + 3, v.w);
    }
    __syncthreads();

    // ---- Phase 3: write the owned output tile once, coalesced ----
    float4* out4 = (float4*)(out + ((size_t)b * NN + a0) * DD);
    const float4* a4 = (const float4*)acc;
    #pragma unroll
    for (int i = tid; i < ACH * DD / 4; i += NTHR)
        out4[i] = a4[i];
}

extern "C" void kernel_launch(void* const* d_in, const int* in_sizes, int n_in,
                              void* d_out, int out_size, void* d_ws, size_t ws_size,
                              hipStream_t stream) {
    const float* messages = (const float*)d_in[0];
    const int*   tgt      = (const int*)d_in[1];
    // d_in[2] (atom_features_ref) is shape-only; never dereferenced.
    float* out = (float*)d_out;

    dim3 grid(BB * NCH);   // 1024 blocks: one per (batch, 64-atom chunk)
    scatter_bin_kernel<<<grid, NTHR, 0, stream>>>(messages, tgt, out);
}

// Round 8
// 345.017 us; speedup vs baseline: 1.0279x; 1.0279x over previous
//
#include <hip/hip_runtime.h>

// Scatter-add edge messages to target atoms per batch:
//   messages: (B=32, E=8192, D=128) f32
//   tgt_indices: (B, E) int32 in [0, N)
//   atom_features_ref: (B, N=2048, D=128) f32  -- shape-only, never read
//   out: (B, N, D) f32
#define BB   32
#define EE   8192
#define NN   2048
#define DD   128
#define ACH  64              // atoms per block
#define NCH  (NN / ACH)      // 32 chunks per batch
#define NTHR 512             // 8 waves
#define CAP  1024            // edge-list capacity: E[n]=256, sigma~16 -> 48-sigma headroom

// LDS: acc 32 KiB + lst 4 KiB + cnt -> ~36.2 KiB => 4 blocks/CU => 32 waves/CU (100%),
// and the whole 1024-block grid is co-resident (single residency round).
__global__ __launch_bounds__(NTHR, 8) void scatter_bin_kernel(
    const float* __restrict__ messages,
    const int*   __restrict__ tgt,
    float*       __restrict__ out)
{
    __shared__ float        acc[ACH * DD];   // 32 KiB accumulation tile
    __shared__ unsigned int lst[CAP];        // 4 KiB compacted edge list
    __shared__ unsigned int cnt;

    const int bid = blockIdx.x;
    const int b   = bid / NCH;
    const int a0  = (bid % NCH) * ACH;
    const int tid = threadIdx.x;

    // ---- Phase 0: zero accumulator tile ----
    float4* acc4 = (float4*)acc;
    #pragma unroll
    for (int i = tid; i < ACH * DD / 4; i += NTHR)
        acc4[i] = make_float4(0.f, 0.f, 0.f, 0.f);
    if (tid == 0) cnt = 0u;
    __syncthreads();

    // ---- Phase 1: scan this batch's indices (int4-vectorized), compact ----
    const int4* idx4 = (const int4*)(tgt + b * EE);
    #pragma unroll
    for (int q = tid; q < EE / 4; q += NTHR) {
        int4 v = idx4[q];
        const int e = q * 4;
        unsigned int d;
        d = (unsigned int)(v.x - a0);
        if (d < (unsigned int)ACH) { unsigned p = atomicAdd(&cnt, 1u); if (p < CAP) lst[p] = ((unsigned)(e + 0) << 6) | d; }
        d = (unsigned int)(v.y - a0);
        if (d < (unsigned int)ACH) { unsigned p = atomicAdd(&cnt, 1u); if (p < CAP) lst[p] = ((unsigned)(e + 1) << 6) | d; }
        d = (unsigned int)(v.z - a0);
        if (d < (unsigned int)ACH) { unsigned p = atomicAdd(&cnt, 1u); if (p < CAP) lst[p] = ((unsigned)(e + 2) << 6) | d; }
        d = (unsigned int)(v.w - a0);
        if (d < (unsigned int)ACH) { unsigned p = atomicAdd(&cnt, 1u); if (p < CAP) lst[p] = ((unsigned)(e + 3) << 6) | d; }
    }
    __syncthreads();

    const int     n       = (int)cnt;
    const float4* msg4    = (const float4*)messages;
    const size_t  rowbase = (size_t)b * EE;
    const int     slot    = tid >> 5;   // 16 edge slots in flight
    const int     l       = tid & 31;   // float4 lane within 512 B row

    if (n <= CAP) {
        // ---- Phase 2: gather, 4-deep unrolled for MLP (4 dwordx4 in flight) ----
        int i = slot;
        for (; i + 48 < n; i += 64) {
            unsigned u0 = lst[i], u1 = lst[i + 16], u2 = lst[i + 32], u3 = lst[i + 48];
            float4 v0 = msg4[(rowbase + (u0 >> 6)) * (DD / 4) + l];
            float4 v1 = msg4[(rowbase + (u1 >> 6)) * (DD / 4) + l];
            float4 v2 = msg4[(rowbase + (u2 >> 6)) * (DD / 4) + l];
            float4 v3 = msg4[(rowbase + (u3 >> 6)) * (DD / 4) + l];
            // NOTE: ds_add_f32 here is ~8-way bank-aliased (banks 4*l%32);
            // acceptable while latency-bound — revisit if it shows up.
            float* d0 = &acc[(u0 & 63u) * DD + l * 4];
            atomicAdd(d0 + 0, v0.x); atomicAdd(d0 + 1, v0.y); atomicAdd(d0 + 2, v0.z); atomicAdd(d0 + 3, v0.w);
            float* d1 = &acc[(u1 & 63u) * DD + l * 4];
            atomicAdd(d1 + 0, v1.x); atomicAdd(d1 + 1, v1.y); atomicAdd(d1 + 2, v1.z); atomicAdd(d1 + 3, v1.w);
            float* d2 = &acc[(u2 & 63u) * DD + l * 4];
            atomicAdd(d2 + 0, v2.x); atomicAdd(d2 + 1, v2.y); atomicAdd(d2 + 2, v2.z); atomicAdd(d2 + 3, v2.w);
            float* d3 = &acc[(u3 & 63u) * DD + l * 4];
            atomicAdd(d3 + 0, v3.x); atomicAdd(d3 + 1, v3.y); atomicAdd(d3 + 2, v3.z); atomicAdd(d3 + 3, v3.w);
        }
        for (; i < n; i += 16) {
            unsigned u = lst[i];
            float4 v = msg4[(rowbase + (u >> 6)) * (DD / 4) + l];
            float* d = &acc[(u & 63u) * DD + l * 4];
            atomicAdd(d + 0, v.x); atomicAdd(d + 1, v.y); atomicAdd(d + 2, v.z); atomicAdd(d + 3, v.w);
        }
    } else {
        // ---- Fallback (correct for any index distribution; never expected on
        // uniform-random data): direct rescan, no list.
        const int* idx = tgt + b * EE;
        for (int e = slot; e < EE; e += 16) {
            unsigned d = (unsigned)(idx[e] - a0);   // broadcast load per 32-lane group
            if (d < (unsigned)ACH) {
                float4 v = msg4[(rowbase + e) * (DD / 4) + l];
                float* dst = &acc[d * DD + l * 4];
                atomicAdd(dst + 0, v.x); atomicAdd(dst + 1, v.y); atomicAdd(dst + 2, v.z); atomicAdd(dst + 3, v.w);
            }
        }
    }
    __syncthreads();

    // ---- Phase 3: write owned output tile once, coalesced ----
    float4* out4 = (float4*)(out + ((size_t)b * NN + a0) * DD);
    const float4* a4 = (const float4*)acc;
    #pragma unroll
    for (int i = tid; i < ACH * DD / 4; i += NTHR)
        out4[i] = a4[i];
}

extern "C" void kernel_launch(void* const* d_in, const int* in_sizes, int n_in,
                              void* d_out, int out_size, void* d_ws, size_t ws_size,
                              hipStream_t stream) {
    const float* messages = (const float*)d_in[0];
    const int*   tgt      = (const int*)d_in[1];
    // d_in[2] (atom_features_ref) is shape-only; never dereferenced.
    float* out = (float*)d_out;

    dim3 grid(BB * NCH);   // 1024 blocks: one per (batch, 64-atom chunk)
    scatter_bin_kernel<<<grid, NTHR, 0, stream>>>(messages, tgt, out);
}

// Round 9
// 224.820 us; speedup vs baseline: 1.5774x; 1.5346x over previous
//
#include <hip/hip_runtime.h>

// Scatter-add edge messages to target atoms per batch:
//   messages: (B=32, E=8192, D=128) f32
//   tgt_indices: (B, E) int32 in [0, N)
//   atom_features_ref: (B, N, D) f32  -- shape-only, never read
//   out: (B, N=2048, D=128) f32
//
// R8 post-mortem: per-element LDS atomics (33.5M ds_add_f32 RMWs) were the
// ~190 us wall (~3 cyc/lane RMW; invisible to SQ_LDS_BANK_CONFLICT).
// This version: histogram + prefix-sum + segment scatter (atomics only for
// ~512 counter bumps/block over 64 addresses), then pure register
// accumulation per exclusively-owned atom. No atomics in the hot phase.
#define BB    32
#define EE    8192
#define NN    2048
#define DD    128
#define ACH   64               // atoms per block
#define NCH   (NN / ACH)       // 32 chunks per batch
#define NTHR  512              // 8 waves
#define NWAVE (NTHR / 64)      // 8
#define APW   (ACH / NWAVE)    // 8 atoms owned per wave
#define CAP   1024             // total-match capacity: E[n]=256, sigma~16 -> 48-sigma

__global__ __launch_bounds__(NTHR, 8) void scatter_seg_kernel(
    const float* __restrict__ messages,
    const int*   __restrict__ tgt,
    float*       __restrict__ out)
{
    __shared__ unsigned short lst[CAP];  // edge ids, segmented by atom (2 KiB)
    __shared__ int cnt[ACH];             // per-atom match count
    __shared__ int off[ACH];             // segment start (exclusive prefix)
    __shared__ int cur[ACH];             // scatter cursor
    __shared__ int total;

    const int bid = blockIdx.x;
    const int b   = bid / NCH;
    const int a0  = (bid % NCH) * ACH;
    const int tid = threadIdx.x;
    const int w   = tid >> 6;            // wave 0..7
    const int l   = tid & 63;            // lane 0..63

    // ---- Phase 0: zero histogram ----
    if (tid < ACH) cnt[tid] = 0;
    __syncthreads();

    // ---- Phase 1a: histogram matches per atom (64-address LDS atomics) ----
    const int4* idx4 = (const int4*)(tgt + b * EE);
    for (int q = tid; q < EE / 4; q += NTHR) {
        int4 v = idx4[q];
        unsigned d;
        d = (unsigned)(v.x - a0); if (d < (unsigned)ACH) atomicAdd(&cnt[d], 1);
        d = (unsigned)(v.y - a0); if (d < (unsigned)ACH) atomicAdd(&cnt[d], 1);
        d = (unsigned)(v.z - a0); if (d < (unsigned)ACH) atomicAdd(&cnt[d], 1);
        d = (unsigned)(v.w - a0); if (d < (unsigned)ACH) atomicAdd(&cnt[d], 1);
    }
    __syncthreads();

    // ---- Phase 1b: exclusive prefix sum over 64 counts (wave 0, shfl scan) ----
    if (tid < 64) {
        int c = cnt[tid];
        int s = c;
        #pragma unroll
        for (int sh = 1; sh < 64; sh <<= 1) {
            int t = __shfl_up(s, sh, 64);
            if (tid >= sh) s += t;
        }
        off[tid] = s - c;
        cur[tid] = s - c;
        if (tid == 63) total = s;
    }
    __syncthreads();

    const int tot = total;
    const float2* msg2    = (const float2*)messages;
    const size_t  rowbase = (size_t)b * EE;

    if (tot <= CAP) {
        // ---- Phase 1c: scatter edge ids into per-atom segments ----
        for (int q = tid; q < EE / 4; q += NTHR) {
            int4 v = idx4[q];   // L1/L2-hot rescan
            const int e = q * 4;
            unsigned d;
            d = (unsigned)(v.x - a0); if (d < (unsigned)ACH) { int p = atomicAdd(&cur[d], 1); lst[p] = (unsigned short)(e + 0); }
            d = (unsigned)(v.y - a0); if (d < (unsigned)ACH) { int p = atomicAdd(&cur[d], 1); lst[p] = (unsigned short)(e + 1); }
            d = (unsigned)(v.z - a0); if (d < (unsigned)ACH) { int p = atomicAdd(&cur[d], 1); lst[p] = (unsigned short)(e + 2); }
            d = (unsigned)(v.w - a0); if (d < (unsigned)ACH) { int p = atomicAdd(&cur[d], 1); lst[p] = (unsigned short)(e + 3); }
        }
        __syncthreads();

        // ---- Phase 2: wave-owned atoms, register accumulation, zero atomics.
        // d, beg, n are wave-uniform (LDS broadcast) -> no divergence.
        // Each row load: 64 lanes x float2 = 512 B coalesced; 4-deep unroll.
        for (int k = 0; k < APW; ++k) {
            const int d   = w + NWAVE * k;
            const int beg = off[d];
            const int n   = cnt[d];
            float2 s = make_float2(0.f, 0.f);
            int j = 0;
            for (; j + 4 <= n; j += 4) {
                int e0 = lst[beg + j + 0], e1 = lst[beg + j + 1];
                int e2 = lst[beg + j + 2], e3 = lst[beg + j + 3];
                float2 v0 = msg2[(rowbase + e0) * (DD / 2) + l];
                float2 v1 = msg2[(rowbase + e1) * (DD / 2) + l];
                float2 v2 = msg2[(rowbase + e2) * (DD / 2) + l];
                float2 v3 = msg2[(rowbase + e3) * (DD / 2) + l];
                s.x += (v0.x + v1.x) + (v2.x + v3.x);
                s.y += (v0.y + v1.y) + (v2.y + v3.y);
            }
            for (; j < n; ++j) {
                int e = lst[beg + j];
                float2 v = msg2[(rowbase + e) * (DD / 2) + l];
                s.x += v.x; s.y += v.y;
            }
            // Exclusive owner writes the row once (also zeros empty atoms).
            ((float2*)out)[((size_t)b * NN + a0 + d) * (DD / 2) + l] = s;
        }
    } else {
        // ---- Fallback (any adversarial distribution; never on uniform data):
        // atomic-free full rescan per owned atom.
        const int* idx = tgt + b * EE;
        for (int k = 0; k < APW; ++k) {
            const int d      = w + NWAVE * k;
            const int target = a0 + d;
            float2 s = make_float2(0.f, 0.f);
            for (int e = 0; e < EE; ++e) {
                if (idx[e] == target) {   // uniform branch (broadcast load)
                    float2 v = msg2[(rowbase + e) * (DD / 2) + l];
                    s.x += v.x; s.y += v.y;
                }
            }
            ((float2*)out)[((size_t)b * NN + a0 + d) * (DD / 2) + l] = s;
        }
    }
}

extern "C" void kernel_launch(void* const* d_in, const int* in_sizes, int n_in,
                              void* d_out, int out_size, void* d_ws, size_t ws_size,
                              hipStream_t stream) {
    const float* messages = (const float*)d_in[0];
    const int*   tgt      = (const int*)d_in[1];
    // d_in[2] (atom_features_ref) is shape-only; never dereferenced.
    float* out = (float*)d_out;

    dim3 grid(BB * NCH);   // 1024 blocks: one per (batch, 64-atom chunk)
    scatter_seg_kernel<<<grid, NTHR, 0, stream>>>(messages, tgt, out);
}

// Round 10
// 223.713 us; speedup vs baseline: 1.5852x; 1.0049x over previous
//
#include <hip/hip_runtime.h>

// Scatter-add edge messages to target atoms per batch:
//   messages: (B=32, E=8192, D=128) f32
//   tgt_indices: (B, E) int32 in [0, N)
//   atom_features_ref: (B, N, D) f32  -- shape-only, never read
//   out: (B, N=2048, D=128) f32
//
// R8->R9: removing per-element LDS atomics cut kernel 191 -> ~70 us (confirmed).
// R9->R10: Phase-2 restructure. Mean segment = E/N = 4 edges/atom, so deep
// unrolls never engaged and float2 loads gave only 8 B/lane. Now each
// HALF-WAVE owns one atom: 32 lanes x float4 = one full 512 B row per load
// instruction; the two halves walk different segments concurrently (divergent
// loop costs max(n0,n1), not the sum); stores are full-wave (two rows/instr).
// lst sized to EE (u16) => overflow fallback deleted; LDS ~17 KiB, 4 blk/CU.
#define BB    32
#define EE    8192
#define NN    2048
#define DD    128
#define ACH   64               // atoms per block
#define NCH   (NN / ACH)       // 32 chunks per batch
#define NTHR  512              // 8 waves
#define NWAVE (NTHR / 64)      // 8
#define APW   (ACH / NWAVE)    // 8 atoms owned per wave

__global__ __launch_bounds__(NTHR, 8) void scatter_seg_kernel(
    const float* __restrict__ messages,
    const int*   __restrict__ tgt,
    float*       __restrict__ out)
{
    __shared__ unsigned short lst[EE];   // 16 KiB — holds worst case (all edges)
    __shared__ int cnt[ACH];             // per-atom match count
    __shared__ int off[ACH];             // segment start (exclusive prefix)
    __shared__ int cur[ACH];             // scatter cursor

    const int bid = blockIdx.x;
    const int b   = bid / NCH;
    const int a0  = (bid % NCH) * ACH;
    const int tid = threadIdx.x;
    const int w   = tid >> 6;            // wave 0..7
    const int l   = tid & 63;            // lane 0..63
    const int h   = l >> 5;              // half-wave 0/1
    const int c   = l & 31;              // float4 column within a row

    // ---- Phase 0: zero histogram ----
    if (tid < ACH) cnt[tid] = 0;
    __syncthreads();

    // ---- Phase 1a: histogram matches per atom (64-address LDS atomics) ----
    const int4* idx4 = (const int4*)(tgt + b * EE);
    for (int q = tid; q < EE / 4; q += NTHR) {
        int4 v = idx4[q];
        unsigned d;
        d = (unsigned)(v.x - a0); if (d < (unsigned)ACH) atomicAdd(&cnt[d], 1);
        d = (unsigned)(v.y - a0); if (d < (unsigned)ACH) atomicAdd(&cnt[d], 1);
        d = (unsigned)(v.z - a0); if (d < (unsigned)ACH) atomicAdd(&cnt[d], 1);
        d = (unsigned)(v.w - a0); if (d < (unsigned)ACH) atomicAdd(&cnt[d], 1);
    }
    __syncthreads();

    // ---- Phase 1b: exclusive prefix sum over 64 counts (wave 0, shfl scan) ----
    if (tid < 64) {
        int cc = cnt[tid];
        int s  = cc;
        #pragma unroll
        for (int sh = 1; sh < 64; sh <<= 1) {
            int t = __shfl_up(s, sh, 64);
            if (tid >= sh) s += t;
        }
        off[tid] = s - cc;
        cur[tid] = s - cc;
    }
    __syncthreads();

    // ---- Phase 1c: scatter edge ids into per-atom segments (idx L1/L2-hot) ----
    for (int q = tid; q < EE / 4; q += NTHR) {
        int4 v = idx4[q];
        const int e = q * 4;
        unsigned d;
        d = (unsigned)(v.x - a0); if (d < (unsigned)ACH) { int p = atomicAdd(&cur[d], 1); lst[p] = (unsigned short)(e + 0); }
        d = (unsigned)(v.y - a0); if (d < (unsigned)ACH) { int p = atomicAdd(&cur[d], 1); lst[p] = (unsigned short)(e + 1); }
        d = (unsigned)(v.z - a0); if (d < (unsigned)ACH) { int p = atomicAdd(&cur[d], 1); lst[p] = (unsigned short)(e + 2); }
        d = (unsigned)(v.w - a0); if (d < (unsigned)ACH) { int p = atomicAdd(&cur[d], 1); lst[p] = (unsigned short)(e + 3); }
    }
    __syncthreads();

    // ---- Phase 2: half-wave-owned atoms, register accumulation, no atomics.
    // Each row load: 32 lanes x float4 = full 512 B row, coalesced.
    // Halves diverge on segment length -> cost is max(n0,n1) per pass.
    const float4* msg4    = (const float4*)messages;
    const size_t  rowbase = (size_t)b * EE;
    float4*       out4    = (float4*)out;

    #pragma unroll
    for (int k = 0; k < APW / 2; ++k) {         // 4 passes, 2 atoms per pass
        const int d   = w * APW + 2 * k + h;    // half-uniform atom id
        const int beg = off[d];
        const int n   = cnt[d];
        float4 s = make_float4(0.f, 0.f, 0.f, 0.f);
        int j = 0;
        for (; j + 4 <= n; j += 4) {            // 4 full rows in flight per half
            int e0 = lst[beg + j + 0], e1 = lst[beg + j + 1];
            int e2 = lst[beg + j + 2], e3 = lst[beg + j + 3];
            float4 v0 = msg4[(rowbase + e0) * (DD / 4) + c];
            float4 v1 = msg4[(rowbase + e1) * (DD / 4) + c];
            float4 v2 = msg4[(rowbase + e2) * (DD / 4) + c];
            float4 v3 = msg4[(rowbase + e3) * (DD / 4) + c];
            s.x += (v0.x + v1.x) + (v2.x + v3.x);
            s.y += (v0.y + v1.y) + (v2.y + v3.y);
            s.z += (v0.z + v1.z) + (v2.z + v3.z);
            s.w += (v0.w + v1.w) + (v2.w + v3.w);
        }
        for (; j < n; ++j) {
            int e = lst[beg + j];
            float4 v = msg4[(rowbase + e) * (DD / 4) + c];
            s.x += v.x; s.y += v.y; s.z += v.z; s.w += v.w;
        }
        // Exclusive owner writes the row once (also zeros empty atoms).
        // Both halves store together: 64 lanes x 16 B = 1 KiB per instruction.
        out4[((size_t)b * NN + a0 + d) * (DD / 4) + c] = s;
    }
}

extern "C" void kernel_launch(void* const* d_in, const int* in_sizes, int n_in,
                              void* d_out, int out_size, void* d_ws, size_t ws_size,
                              hipStream_t stream) {
    const float* messages = (const float*)d_in[0];
    const int*   tgt      = (const int*)d_in[1];
    // d_in[2] (atom_features_ref) is shape-only; never dereferenced.
    float* out = (float*)d_out;

    dim3 grid(BB * NCH);   // 1024 blocks: one per (batch, 64-atom chunk)
    scatter_seg_kernel<<<grid, NTHR, 0, stream>>>(messages, tgt, out);
}

// Round 12
// 221.352 us; speedup vs baseline: 1.6022x; 1.0107x over previous
//
#include <hip/hip_runtime.h>

// Scatter-add edge messages to target atoms per batch:
//   messages: (B=32, E=8192, D=128) f32
//   tgt_indices: (B, E) int32 in [0, N)
//   atom_features_ref: (B, N, D) f32  -- shape-only, never read
//   out: (B, N=2048, D=128) f32
//
// Ladder: R8 191us (33.5M LDS value-atomics = wall) -> R9 ~70us (segment sort,
// register accum) -> R10 ~70us (float4 half-wave gather: NEUTRAL -> Phase 2
// not load-width-limited). R11: collapse Phase 1 from {histogram scan, prefix,
// scatter scan, 4 barriers} to ONE scan with fixed-capacity slots.
// Per-atom occupancy ~ Poisson(E/N = 4); P(n > 32) ~ 1e-22 -> slots of 32
// with a correctness-preserving per-atom rescan fallback that never fires on
// real data. LDS ~4.3 KiB.
#define BB    32
#define EE    8192
#define NN    2048
#define DD    128
#define ACH   64               // atoms per block
#define NCH   (NN / ACH)       // 32 chunks per batch
#define NTHR  512              // 8 waves
#define NWAVE (NTHR / 64)      // 8
#define APW   (ACH / NWAVE)    // 8 atoms owned per wave
#define SLOT  32               // edge slots per atom (mean 4, 1e-22 overflow)

__global__ __launch_bounds__(NTHR, 8) void scatter_slot_kernel(
    const float* __restrict__ messages,
    const int*   __restrict__ tgt,
    float*       __restrict__ out)
{
    __shared__ unsigned short lst[ACH][SLOT];  // 4 KiB slotted edge ids
    __shared__ int            cnt[ACH];        // per-atom cursor/count

    const int bid = blockIdx.x;
    const int b   = bid / NCH;
    const int a0  = (bid % NCH) * ACH;
    const int tid = threadIdx.x;
    const int w   = tid >> 6;            // wave 0..7
    const int l   = tid & 63;            // lane 0..63
    const int h   = l >> 5;              // half-wave 0/1
    const int c   = l & 31;              // float4 column within a row

    if (tid < ACH) cnt[tid] = 0;
    __syncthreads();

    // ---- Phase 1: single scan; slot-insert matching edge ids ----
    const int4* idx4 = (const int4*)(tgt + b * EE);
    for (int q = tid; q < EE / 4; q += NTHR) {
        int4 v = idx4[q];
        const int e = q * 4;
        unsigned d;
        d = (unsigned)(v.x - a0); if (d < (unsigned)ACH) { int p = atomicAdd(&cnt[d], 1); if (p < SLOT) lst[d][p] = (unsigned short)(e + 0); }
        d = (unsigned)(v.y - a0); if (d < (unsigned)ACH) { int p = atomicAdd(&cnt[d], 1); if (p < SLOT) lst[d][p] = (unsigned short)(e + 1); }
        d = (unsigned)(v.z - a0); if (d < (unsigned)ACH) { int p = atomicAdd(&cnt[d], 1); if (p < SLOT) lst[d][p] = (unsigned short)(e + 2); }
        d = (unsigned)(v.w - a0); if (d < (unsigned)ACH) { int p = atomicAdd(&cnt[d], 1); if (p < SLOT) lst[d][p] = (unsigned short)(e + 3); }
    }
    __syncthreads();

    // ---- Phase 2: half-wave-owned atoms, register accumulation, no atomics.
    // Each row load: 32 lanes x float4 = full 512 B row, coalesced. The two
    // halves walk different segments concurrently (cost = max(n0, n1)).
    const float4* msg4    = (const float4*)messages;
    const size_t  rowbase = (size_t)b * EE;
    float4*       out4    = (float4*)out;

    #pragma unroll
    for (int k = 0; k < APW / 2; ++k) {         // 4 passes, 2 atoms per pass
        const int d = w * APW + 2 * k + h;      // halves own consecutive atoms
        const int n = cnt[d];
        float4 s = make_float4(0.f, 0.f, 0.f, 0.f);
        if (n <= SLOT) {
            int j = 0;
            for (; j + 4 <= n; j += 4) {        // 4 full rows in flight per half
                int e0 = lst[d][j + 0], e1 = lst[d][j + 1];
                int e2 = lst[d][j + 2], e3 = lst[d][j + 3];
                float4 v0 = msg4[(rowbase + e0) * (DD / 4) + c];
                float4 v1 = msg4[(rowbase + e1) * (DD / 4) + c];
                float4 v2 = msg4[(rowbase + e2) * (DD / 4) + c];
                float4 v3 = msg4[(rowbase + e3) * (DD / 4) + c];
                s.x += (v0.x + v1.x) + (v2.x + v3.x);
                s.y += (v0.y + v1.y) + (v2.y + v3.y);
                s.z += (v0.z + v1.z) + (v2.z + v3.z);
                s.w += (v0.w + v1.w) + (v2.w + v3.w);
            }
            for (; j < n; ++j) {
                int e = lst[d][j];
                float4 v = msg4[(rowbase + e) * (DD / 4) + c];
                s.x += v.x; s.y += v.y; s.z += v.z; s.w += v.w;
            }
        } else {
            // Overflow fallback (correct for any distribution; P ~ 1e-22 on
            // uniform data): rescan all indices for this atom only.
            const int* idx = tgt + b * EE;
            const int target = a0 + d;
            for (int e = 0; e < EE; ++e) {
                if (idx[e] == target) {
                    float4 v = msg4[(rowbase + e) * (DD / 4) + c];
                    s.x += v.x; s.y += v.y; s.z += v.z; s.w += v.w;
                }
            }
        }
        // Exclusive owner writes the row once (also zeros empty atoms).
        // Both halves store together: 64 lanes x 16 B = 1 KiB contiguous.
        out4[((size_t)b * NN + a0 + d) * (DD / 4) + c] = s;
    }
}

extern "C" void kernel_launch(void* const* d_in, const int* in_sizes, int n_in,
                              void* d_out, int out_size, void* d_ws, size_t ws_size,
                              hipStream_t stream) {
    const float* messages = (const float*)d_in[0];
    const int*   tgt      = (const int*)d_in[1];
    // d_in[2] (atom_features_ref) is shape-only; never dereferenced.
    float* out = (float*)d_out;

    dim3 grid(BB * NCH);   // 1024 blocks: one per (batch, 64-atom chunk)
    scatter_slot_kernel<<<grid, NTHR, 0, stream>>>(messages, tgt, out);
}

// Round 14
// 221.225 us; speedup vs baseline: 1.6031x; 1.0006x over previous
//
#include <hip/hip_runtime.h>

// Scatter-add edge messages to target atoms per batch:
//   messages: (B=32, E=8192, D=128) f32
//   tgt_indices: (B, E) int32 in [0, N)
//   atom_features_ref: (B, N, D) f32  -- shape-only, never read
//   out: (B, N=2048, D=128) f32
//
// Ladder: R8 191us (33.5M LDS value-atomics) -> R9 ~70us (segment sort, reg
// accum) -> R10 ~70us (float4 half-wave rows: NEUTRAL) -> R12 ~67us (1-scan
// slotted Phase 1: ~2us -> Phase 1 exonerated). R13: Phase-2 MLP experiment.
// Mean segment = Poisson(4) edges, so per-segment walks hold only ~1-2 loads
// in flight. Now each half-wave walks its FOUR owned segments in lockstep
// (slot index j, 2-deep) -> up to 8 independent 512B row loads in flight,
// issued branchlessly (select-index, predicated accumulate).
#define BB    32
#define EE    8192
#define NN    2048
#define DD    128
#define ACH   64               // atoms per block
#define NCH   (NN / ACH)       // 32 chunks per batch
#define NTHR  512              // 8 waves
#define SLOT  32               // edge slots per atom (mean 4, P(n>32)~1e-22)

__global__ __launch_bounds__(NTHR, 6) void scatter_ilv_kernel(
    const float* __restrict__ messages,
    const int*   __restrict__ tgt,
    float*       __restrict__ out)
{
    __shared__ unsigned short lst[ACH][SLOT];  // 4 KiB slotted edge ids
    __shared__ int            cnt[ACH];        // per-atom cursor/count

    const int bid = blockIdx.x;
    const int b   = bid / NCH;
    const int a0  = (bid % NCH) * ACH;
    const int tid = threadIdx.x;
    const int w   = tid >> 6;            // wave 0..7
    const int l   = tid & 63;            // lane 0..63
    const int h   = l >> 5;              // half-wave 0/1
    const int c   = l & 31;              // float4 column within a row

    if (tid < ACH) cnt[tid] = 0;
    __syncthreads();

    // ---- Phase 1: single scan; slot-insert matching edge ids ----
    const int4* idx4 = (const int4*)(tgt + b * EE);
    for (int q = tid; q < EE / 4; q += NTHR) {
        int4 v = idx4[q];
        const int e = q * 4;
        unsigned d;
        d = (unsigned)(v.x - a0); if (d < (unsigned)ACH) { int p = atomicAdd(&cnt[d], 1); if (p < SLOT) lst[d][p] = (unsigned short)(e + 0); }
        d = (unsigned)(v.y - a0); if (d < (unsigned)ACH) { int p = atomicAdd(&cnt[d], 1); if (p < SLOT) lst[d][p] = (unsigned short)(e + 1); }
        d = (unsigned)(v.z - a0); if (d < (unsigned)ACH) { int p = atomicAdd(&cnt[d], 1); if (p < SLOT) lst[d][p] = (unsigned short)(e + 2); }
        d = (unsigned)(v.w - a0); if (d < (unsigned)ACH) { int p = atomicAdd(&cnt[d], 1); if (p < SLOT) lst[d][p] = (unsigned short)(e + 3); }
    }
    __syncthreads();

    // ---- Phase 2: each half-wave owns 4 atoms (d_k = w*8 + 2k + h) and
    // walks all 4 segments in lockstep, 2 slot-steps deep: 8 loads in flight.
    const float4* msg4    = (const float4*)messages;
    const size_t  rowbase = (size_t)b * EE;
    float4*       out4    = (float4*)out;

    const int d0 = w * 8 + 0 + h, d1 = w * 8 + 2 + h;
    const int d2 = w * 8 + 4 + h, d3 = w * 8 + 6 + h;
    const int n0 = cnt[d0], n1 = cnt[d1], n2 = cnt[d2], n3 = cnt[d3];
    // Clamp overflowed segments out of the main loop (fallback handles them).
    const int m0 = (n0 <= SLOT) ? n0 : 0, m1 = (n1 <= SLOT) ? n1 : 0;
    const int m2 = (n2 <= SLOT) ? n2 : 0, m3 = (n3 <= SLOT) ? n3 : 0;
    const int nm = max(max(m0, m1), max(m2, m3));

    float4 s0 = make_float4(0.f, 0.f, 0.f, 0.f), s1 = s0, s2 = s0, s3 = s0;

    for (int j = 0; j < nm; j += 2) {
        const int ja = j;
        const int jb = min(j + 1, SLOT - 1);   // safe LDS read when j+1==SLOT
        // Select-index: read slot (in-bounds), redirect drained segments to
        // row 0 (L1-hot dummy) so the 8 loads issue as one straight-line batch.
        int e0a = lst[d0][ja]; e0a = (ja < m0) ? e0a : 0;
        int e1a = lst[d1][ja]; e1a = (ja < m1) ? e1a : 0;
        int e2a = lst[d2][ja]; e2a = (ja < m2) ? e2a : 0;
        int e3a = lst[d3][ja]; e3a = (ja < m3) ? e3a : 0;
        int e0b = lst[d0][jb]; e0b = (j + 1 < m0) ? e0b : 0;
        int e1b = lst[d1][jb]; e1b = (j + 1 < m1) ? e1b : 0;
        int e2b = lst[d2][jb]; e2b = (j + 1 < m2) ? e2b : 0;
        int e3b = lst[d3][jb]; e3b = (j + 1 < m3) ? e3b : 0;

        float4 v0a = msg4[(rowbase + e0a) * (DD / 4) + c];
        float4 v1a = msg4[(rowbase + e1a) * (DD / 4) + c];
        float4 v2a = msg4[(rowbase + e2a) * (DD / 4) + c];
        float4 v3a = msg4[(rowbase + e3a) * (DD / 4) + c];
        float4 v0b = msg4[(rowbase + e0b) * (DD / 4) + c];
        float4 v1b = msg4[(rowbase + e1b) * (DD / 4) + c];
        float4 v2b = msg4[(rowbase + e2b) * (DD / 4) + c];
        float4 v3b = msg4[(rowbase + e3b) * (DD / 4) + c];

        if (ja < m0)    { s0.x += v0a.x; s0.y += v0a.y; s0.z += v0a.z; s0.w += v0a.w; }
        if (j + 1 < m0) { s0.x += v0b.x; s0.y += v0b.y; s0.z += v0b.z; s0.w += v0b.w; }
        if (ja < m1)    { s1.x += v1a.x; s1.y += v1a.y; s1.z += v1a.z; s1.w += v1a.w; }
        if (j + 1 < m1) { s1.x += v1b.x; s1.y += v1b.y; s1.z += v1b.z; s1.w += v1b.w; }
        if (ja < m2)    { s2.x += v2a.x; s2.y += v2a.y; s2.z += v2a.z; s2.w += v2a.w; }
        if (j + 1 < m2) { s2.x += v2b.x; s2.y += v2b.y; s2.z += v2b.z; s2.w += v2b.w; }
        if (ja < m3)    { s3.x += v3a.x; s3.y += v3a.y; s3.z += v3a.z; s3.w += v3a.w; }
        if (j + 1 < m3) { s3.x += v3b.x; s3.y += v3b.y; s3.z += v3b.z; s3.w += v3b.w; }
    }

    // ---- Overflow fallback (P ~ 1e-22 on uniform data; correctness only) ----
    if (n0 > SLOT || n1 > SLOT || n2 > SLOT || n3 > SLOT) {
        const int* idx = tgt + b * EE;
        for (int e = 0; e < EE; ++e) {
            int t = idx[e] - a0;
            if (n0 > SLOT && t == d0) { float4 v = msg4[(rowbase + e) * (DD / 4) + c]; s0.x += v.x; s0.y += v.y; s0.z += v.z; s0.w += v.w; }
            if (n1 > SLOT && t == d1) { float4 v = msg4[(rowbase + e) * (DD / 4) + c]; s1.x += v.x; s1.y += v.y; s1.z += v.z; s1.w += v.w; }
            if (n2 > SLOT && t == d2) { float4 v = msg4[(rowbase + e) * (DD / 4) + c]; s2.x += v.x; s2.y += v.y; s2.z += v.z; s2.w += v.w; }
            if (n3 > SLOT && t == d3) { float4 v = msg4[(rowbase + e) * (DD / 4) + c]; s3.x += v.x; s3.y += v.y; s3.z += v.z; s3.w += v.w; }
        }
    }

    // ---- Stores: per k, halves write rows w*8+2k and w*8+2k+1 -> 1 KiB/instr.
    const size_t obase = (size_t)b * NN + a0;
    out4[(obase + d0) * (DD / 4) + c] = s0;
    out4[(obase + d1) * (DD / 4) + c] = s1;
    out4[(obase + d2) * (DD / 4) + c] = s2;
    out4[(obase + d3) * (DD / 4) + c] = s3;
}

extern "C" void kernel_launch(void* const* d_in, const int* in_sizes, int n_in,
                              void* d_out, int out_size, void* d_ws, size_t ws_size,
                              hipStream_t stream) {
    const float* messages = (const float*)d_in[0];
    const int*   tgt      = (const int*)d_in[1];
    // d_in[2] (atom_features_ref) is shape-only; never dereferenced.
    float* out = (float*)d_out;

    dim3 grid(BB * NCH);   // 1024 blocks: one per (batch, 64-atom chunk)
    scatter_ilv_kernel<<<grid, NTHR, 0, stream>>>(messages, tgt, out);
}